// Round 5
// baseline (235.845 us; speedup 1.0000x reference)
//
#include <hip/hip_runtime.h>

// Izhikevich spiking neuron scan — float4 + 4-deep LDS DMA pipeline with
// hand-counted vmcnt waits and raw s_barrier.
//
// x: [T=512, N=65536] f32. out: [T, N] f32 spike train (0.0 / 1.0).
//
// Recurrence per neuron (bit-identical to all verified prior versions):
//   v = (4v^2 + 5v + 1.4 - r + x_t) * DT   (DT = 1/512)
//   r = 0.02 * (0.2v - v) * DT             (uses NEW v)
//   fire = v >= 0.3 ; fire -> v = -0.065, r += 0.008 ; out_t = fire
//
// Round-5 theory: round 4 (2-buffer DMA, tight waits) still stalled at
// WAITVM — per-tile wall ~24k cycles for ~300 cycles of work, meaning
// loaded-system latency >> 900 cy and ~8 KB/block of guaranteed in-flight
// reads is too shallow. This version: float4 everywhere (16 B/lane ds_read
// + NT store, 4 KB contiguous DMA rows), 4 LDS buffers, stages issued 3
// tiles ahead -> up to 24 KB/block (~96 KB/CU) of reads guaranteed in
// flight with loose waits. 16 chunks x 64 blocks = 1024 blocks, 16
// waves/CU (LDS 32 KB/block).
//
// vmcnt ledger (per wave; 2 DMA stages + 2 NT stores per body, all pinned
// by "memory"-clobber asm + sched_barrier so program order = issue order):
//   prologue: stage0(2), stage1(2), stage2(2)
//   body K: WAIT(vm), bar, ds_read x2, lgkmcnt(0), bar, stage(K+3) 2,
//           2 x (step4 + NT store)
//   outstanding after stage(K) at body K's wait =
//     2*#{stages K+1,K+2 that exist} + 2*#{bodies K-3..K-1 that exist}
//   -> K=0:4, K=1:6, K=2:8, K=3..13:10, K=14:8, K=15:6.
//   (Warmup loads are fully consumed (in-order vm returns) before the
//   prologue, so they contribute 0.)
//
// Buffer-reuse safety: stage(K+3) (issued after body K's 2nd barrier)
// overwrites buf[(K+3)&3], last read at body K-1 before body K-1's 2nd
// barrier; body K's 1st barrier orders those reads before this write.
//
// Time-split justification (verified absmax=0 four times): the map
// contracts prior state by ~(5/512)/step; 8 warmup steps shrink any
// init-state error below fp32 ulp.

#define T_STEPS 512
#define N_NEUR  65536
#define N4      (N_NEUR / 4)     // 16384 float4 columns
#define DT      (1.0f / 512.0f)
#define NCHUNK  16
#define TCH     (T_STEPS / NCHUNK)   // 32 timesteps per chunk
#define WARM    8
#define NT      2                // timesteps per LDS tile
#define NTILES  (TCH / NT)       // 16 tiles per chunk
#define NBUF    4                // LDS tile buffers (pipeline depth 3)
#define ROWB    4096             // bytes per timestep row per block (256 x 16B)
#define TILEB   (NT * ROWB)      // 8192 B per tile buffer
#define RSTR    ((size_t)N_NEUR * 4)  // 262144 B between timestep rows

typedef float v4f __attribute__((ext_vector_type(4)));

template <int N>
__device__ __forceinline__ void waitvm() {
    if constexpr (N == 4)       asm volatile("s_waitcnt vmcnt(4)" ::: "memory");
    else if constexpr (N == 6)  asm volatile("s_waitcnt vmcnt(6)" ::: "memory");
    else if constexpr (N == 8)  asm volatile("s_waitcnt vmcnt(8)" ::: "memory");
    else                        asm volatile("s_waitcnt vmcnt(10)" ::: "memory");
}

__device__ __forceinline__ constexpr int vm_for(int K) {
    const int s = 15 - K;
    const int stages = s > 2 ? 2 : (s < 0 ? 0 : s);
    const int stores = K > 3 ? 3 : K;
    return 2 * stages + 2 * stores;
}

__device__ __forceinline__ void gll16(const void* g, void* l) {
    __builtin_amdgcn_global_load_lds(
        (const __attribute__((address_space(1))) void*)g,
        (__attribute__((address_space(3))) void*)l, 16, 0, 0);
}

__device__ __forceinline__ float izi_step(float xt, float& v, float& r) {
    v = (4.0f * v * v + 5.0f * v + 1.4f - r + xt) * DT;
    r = 0.02f * (0.2f * v - v) * DT;
    const bool fire = v >= 0.3f;
    if (fire) { v = -0.065f; r += 0.008f; }
    return fire ? 1.0f : 0.0f;
}

__device__ __forceinline__ v4f izi_step4(const v4f xt, v4f& v, v4f& r) {
    v4f o;
    float a, b;
    a = v.x; b = r.x; o.x = izi_step(xt.x, a, b); v.x = a; r.x = b;
    a = v.y; b = r.y; o.y = izi_step(xt.y, a, b); v.y = a; r.y = b;
    a = v.z; b = r.z; o.z = izi_step(xt.z, a, b); v.z = a; r.z = b;
    a = v.w; b = r.w; o.w = izi_step(xt.w, a, b); v.w = a; r.w = b;
    return o;
}

// Wave w stages quarter w of tile `tile`: row (w>>1), half (w&1) — two
// 1 KB DMAs (4 KB contiguous per row across waves 2k,2k+1).
__device__ __forceinline__ void stage_tile_part(const char* xb, char* smem,
                                                int tile, int tstart, int w, int lane) {
    const int t = tstart + tile * NT + (w >> 1);
    const char* g = xb + (size_t)t * RSTR + (w & 1) * 2048 + lane * 16;
    char* l = smem + (size_t)(tile & (NBUF - 1)) * TILEB
                   + (w >> 1) * ROWB + (w & 1) * 2048 + lane * 16;
    gll16(g, l);
    gll16(g + 1024, l + 1024);
}

template <int K>
__device__ __forceinline__ void tile_body(const char* xb, char* smem, v4f* outp,
                                          int tid, int lane, int w, int tstart,
                                          v4f& v, v4f& r) {
    // 1. wait for own stage(K) DMAs (loose: up to 3 stages + 6 stores float).
    waitvm<vm_for(K)>();
    __builtin_amdgcn_s_barrier();          // all waves' stage(K) landed
    __builtin_amdgcn_sched_barrier(0);

    // 2. read tile K's 2 rows (ds_read_b128 each), then release the buffer.
    const char* base = smem + (size_t)(K & (NBUF - 1)) * TILEB + tid * 16;
    const v4f xs0 = *(const v4f*)(base);
    const v4f xs1 = *(const v4f*)(base + ROWB);
    asm volatile("s_waitcnt lgkmcnt(0)" ::: "memory");
    __builtin_amdgcn_s_barrier();          // all waves done reading buf[K&3]
    __builtin_amdgcn_sched_barrier(0);

    // 3. re-stage 3 tiles ahead into the buffer freed at body K-1.
    if constexpr (K + 3 < NTILES)
        stage_tile_part(xb, smem, K + 3, tstart, w, lane);

    // 4. recurrence + non-temporal float4 stores (output never re-read).
    const int t0 = tstart + K * NT;
    const v4f o0 = izi_step4(xs0, v, r);
    __builtin_nontemporal_store(o0, outp + (size_t)t0 * N4);
    const v4f o1 = izi_step4(xs1, v, r);
    __builtin_nontemporal_store(o1, outp + (size_t)(t0 + 1) * N4);
}

__global__ __launch_bounds__(256, 4) void izi_kernel(const v4f* __restrict__ x,
                                                     v4f* __restrict__ out) {
    __shared__ __align__(16) char smem[NBUF * TILEB];   // 32 KiB
    const int tid = threadIdx.x;
    const int lane = tid & 63;
    const int w = tid >> 6;                 // wave 0..3
    const int bx = blockIdx.x;              // 0..63: block's 1024-neuron slab
    const int c = blockIdx.y;               // time chunk 0..15
    const int tstart = c * TCH;

    const char* xb = (const char*)x + (size_t)bx * ROWB;   // block row base
    v4f* outp = out + (size_t)bx * 256 + tid;              // thread's column

    v4f v; v.x = v.y = v.z = v.w = -0.065f;
    v4f r; r.x = r.y = r.z = r.w = 0.0f;

    if (c > 0) {
        #pragma unroll
        for (int t = tstart - WARM; t < tstart; ++t) {
            const v4f xt = x[(size_t)t * N4 + bx * 256 + tid];
            (void)izi_step4(xt, v, r);
        }
    }
    // Warmup loads fully consumed (in-order vm returns) -> vmcnt 0 here.
    __builtin_amdgcn_sched_barrier(0);

    // Prologue: stage tiles 0,1,2 (6 DMAs per wave ledger: 2 each).
    stage_tile_part(xb, smem, 0, tstart, w, lane);
    stage_tile_part(xb, smem, 1, tstart, w, lane);
    stage_tile_part(xb, smem, 2, tstart, w, lane);

    tile_body< 0>(xb, smem, outp, tid, lane, w, tstart, v, r);
    tile_body< 1>(xb, smem, outp, tid, lane, w, tstart, v, r);
    tile_body< 2>(xb, smem, outp, tid, lane, w, tstart, v, r);
    tile_body< 3>(xb, smem, outp, tid, lane, w, tstart, v, r);
    tile_body< 4>(xb, smem, outp, tid, lane, w, tstart, v, r);
    tile_body< 5>(xb, smem, outp, tid, lane, w, tstart, v, r);
    tile_body< 6>(xb, smem, outp, tid, lane, w, tstart, v, r);
    tile_body< 7>(xb, smem, outp, tid, lane, w, tstart, v, r);
    tile_body< 8>(xb, smem, outp, tid, lane, w, tstart, v, r);
    tile_body< 9>(xb, smem, outp, tid, lane, w, tstart, v, r);
    tile_body<10>(xb, smem, outp, tid, lane, w, tstart, v, r);
    tile_body<11>(xb, smem, outp, tid, lane, w, tstart, v, r);
    tile_body<12>(xb, smem, outp, tid, lane, w, tstart, v, r);
    tile_body<13>(xb, smem, outp, tid, lane, w, tstart, v, r);
    tile_body<14>(xb, smem, outp, tid, lane, w, tstart, v, r);
    tile_body<15>(xb, smem, outp, tid, lane, w, tstart, v, r);
}

extern "C" void kernel_launch(void* const* d_in, const int* in_sizes, int n_in,
                              void* d_out, int out_size, void* d_ws, size_t ws_size,
                              hipStream_t stream) {
    const v4f* x = (const v4f*)d_in[0];
    v4f* out = (v4f*)d_out;
    // grid: 64 neuron-slabs x 16 time-chunks = 1024 blocks (4/CU, 16
    // waves/CU; LDS 32 KiB/block caps residency at 5 — not binding).
    izi_kernel<<<dim3(N_NEUR / 1024, NCHUNK), dim3(256), 0, stream>>>(x, out);
}